// Round 9
// baseline (373.397 us; speedup 1.0000x reference)
//
#include <hip/hip_runtime.h>

#define E   128
#define HD  32
#define NB  512
#define NN  65536
#define TT  (NB + NN)   // 66048 tokens: [0,NB) metal, [NB,TT) nodes
#define TE  ((size_t)TT * 128)
#define WMAT 16384      // shorts per matrix in frag-ready layout: 4*8*64*8

typedef __attribute__((ext_vector_type(8))) short short8;
typedef __attribute__((ext_vector_type(4))) float f32x4;

__device__ __forceinline__ unsigned short f2bf_rne(float x) {
  unsigned u = __float_as_uint(x);
  return (unsigned short)((u + 0x7FFFu + ((u >> 16) & 1u)) >> 16);
}
__device__ __forceinline__ void split_bf(float x, unsigned short& h, unsigned short& l) {
  h = f2bf_rne(x);
  float hf = __uint_as_float(((unsigned)h) << 16);
  l = f2bf_rne(x - hf);
}

// start[b] = first node index of graph b (batch sorted); start[NB] = NN.
__global__ void k_starts(const int* __restrict__ batch, int* __restrict__ start) {
  int i = blockIdx.x * blockDim.x + threadIdx.x;
  if (i >= NN) return;
  int bi = batch[i];
  int bp = (i == 0) ? -1 : batch[i - 1];
  for (int b = bp + 1; b <= bi; ++b) start[b] = i;
  if (i == NN - 1)
    for (int b = bi + 1; b <= NB; ++b) start[b] = NN;
}

// seq row of token t: metal g -> start[g]+g ; node i -> i + batch[i] + 1
__global__ void k_seqmap(const int* __restrict__ batch, const int* __restrict__ start,
                         int* __restrict__ seqmap) {
  int t = blockIdx.x * 256 + threadIdx.x;
  if (t >= TT) return;
  seqmap[t] = (t < NB) ? (start[t] + t) : (t - NB + batch[t - NB] + 1);
}

// Split weights to hi/lo bf16 in MFMA-frag-ready order:
//   Wf[mat][ks][nt][lane][jj]; mat: 0=Wq 1=Wk 2=in_q 3=in_k 4=in_v 5=out_w.
__global__ void k_wconv(const float* __restrict__ Wq, const float* __restrict__ Wk,
                        const float* __restrict__ in_w, const float* __restrict__ out_w,
                        unsigned short* __restrict__ Wfh, unsigned short* __restrict__ Wfl) {
  int idx = blockIdx.x * 256 + threadIdx.x;   // < 768*128
  int r = idx >> 7, k = idx & 127;
  float v;
  if (r < 128)      v = Wq[r * 128 + k];
  else if (r < 256) v = Wk[(r - 128) * 128 + k];
  else if (r < 640) v = in_w[(r - 256) * 128 + k];
  else              v = out_w[(r - 640) * 128 + k];
  unsigned short h, l;
  split_bf(v, h, l);
  int mat = r >> 7, j = r & 127;
  int ks = k >> 5, quad = (k >> 3) & 3, jj = k & 7;
  int nt = j >> 4, lrow = j & 15;
  int lane = quad * 16 + lrow;
  size_t di = (size_t)mat * WMAT + (((ks * 8 + nt) * 64 + lane) * 8 + jj);
  Wfh[di] = h;
  Wfl[di] = l;
}

// Pre-split token matrix (metal then nodes) into bf16 hi/lo, token order.
__global__ void k_xsplit(const float* __restrict__ x, const float* __restrict__ metal_x,
                         unsigned short* __restrict__ Xh, unsigned short* __restrict__ Xl) {
  int i = blockIdx.x * 256 + threadIdx.x;     // < TT*32
  int t = i >> 5, seg = i & 31;
  const float* src = (t < NB) ? metal_x + (size_t)t * E + seg * 4
                              : x + (size_t)(t - NB) * E + seg * 4;
  float4 v = *(const float4*)src;
  unsigned short h0, l0, h1, l1, h2, l2, h3, l3;
  split_bf(v.x, h0, l0); split_bf(v.y, h1, l1);
  split_bf(v.z, h2, l2); split_bf(v.w, h3, l3);
  ushort4 hv = {h0, h1, h2, h3}, lv = {l0, l1, l2, l3};
  *(ushort4*)(Xh + (size_t)i * 4) = hv;
  *(ushort4*)(Xl + (size_t)i * 4) = lv;
}

// Fused QKV: per 128-token block computes V, Hq->Q, Hk->K with split-bf16 MFMA.
// X pre-split (pure loads). Hq/Hk live only in regs+LDS (wave-private rows, no
// barriers). W in frag-ready layout (coalesced, L2-hot). Outputs seq-order.
__global__ __launch_bounds__(256, 2)
void k_qkv(const unsigned short* __restrict__ Xh, const unsigned short* __restrict__ Xl,
           const unsigned short* __restrict__ Wfh, const unsigned short* __restrict__ Wfl,
           const float* __restrict__ bq, const float* __restrict__ bk,
           const float* __restrict__ in_b, const int* __restrict__ seqmap,
           unsigned short* __restrict__ Qh, unsigned short* __restrict__ Ql,
           unsigned short* __restrict__ Kh, unsigned short* __restrict__ Kl,
           unsigned short* __restrict__ Vb, float scl2) {
  __shared__ unsigned short Th[128][136];   // 34816 B (136*2B=272B row, 16B-aligned)
  __shared__ unsigned short Tl[128][136];   // 34816 B ; total 68.0 KiB -> 2 blocks/CU
  const int tid = threadIdx.x;
  const int wave = tid >> 6;
  const int lane = tid & 63;
  const int lrow = lane & 15;
  const int quad = lane >> 4;
  const int t0 = blockIdx.x * 128;

  // X A-frags for all ks (kept in regs; reused by V, Hq, Hk).
  short8 xh[4][2], xl[4][2];
  int ro[2][4];
  #pragma unroll
  for (int mt = 0; mt < 2; ++mt) {
    size_t ao = (size_t)(t0 + wave * 32 + mt * 16 + lrow) * 128 + quad * 8;
    #pragma unroll
    for (int ks = 0; ks < 4; ++ks) {
      xh[ks][mt] = *(const short8*)(Xh + ao + ks * 32);
      xl[ks][mt] = *(const short8*)(Xl + ao + ks * 32);
    }
    #pragma unroll
    for (int reg = 0; reg < 4; ++reg)
      ro[mt][reg] = seqmap[t0 + wave * 32 + mt * 16 + quad * 4 + reg];
  }

  f32x4 acc[2][8];

#define GEMM_X(MAT)                                                            \
  _Pragma("unroll")                                                            \
  for (int mt = 0; mt < 2; ++mt)                                               \
    _Pragma("unroll")                                                          \
    for (int nt = 0; nt < 8; ++nt) acc[mt][nt] = (f32x4){0.f, 0.f, 0.f, 0.f};  \
  _Pragma("unroll")                                                            \
  for (int ks = 0; ks < 4; ++ks)                                               \
    _Pragma("unroll")                                                          \
    for (int nt = 0; nt < 8; ++nt) {                                           \
      size_t wb = (size_t)(MAT)*WMAT + (((ks * 8 + nt) * 64 + lane) * 8);      \
      short8 bh = *(const short8*)(Wfh + wb);                                  \
      short8 bl = *(const short8*)(Wfl + wb);                                  \
      _Pragma("unroll")                                                        \
      for (int mt = 0; mt < 2; ++mt) {                                         \
        acc[mt][nt] = __builtin_amdgcn_mfma_f32_16x16x32_bf16(xh[ks][mt], bh, acc[mt][nt], 0, 0, 0); \
        acc[mt][nt] = __builtin_amdgcn_mfma_f32_16x16x32_bf16(xl[ks][mt], bh, acc[mt][nt], 0, 0, 0); \
        acc[mt][nt] = __builtin_amdgcn_mfma_f32_16x16x32_bf16(xh[ks][mt], bl, acc[mt][nt], 0, 0, 0); \
      }                                                                        \
    }

#define GEMM_T(MAT)                                                            \
  _Pragma("unroll")                                                            \
  for (int mt = 0; mt < 2; ++mt)                                               \
    _Pragma("unroll")                                                          \
    for (int nt = 0; nt < 8; ++nt) acc[mt][nt] = (f32x4){0.f, 0.f, 0.f, 0.f};  \
  _Pragma("unroll")                                                            \
  for (int ks = 0; ks < 4; ++ks) {                                             \
    short8 ah[2], al[2];                                                       \
    _Pragma("unroll")                                                          \
    for (int mt = 0; mt < 2; ++mt) {                                           \
      int row = wave * 32 + mt * 16 + lrow;                                    \
      ah[mt] = *(const short8*)&Th[row][ks * 32 + quad * 8];                   \
      al[mt] = *(const short8*)&Tl[row][ks * 32 + quad * 8];                   \
    }                                                                          \
    _Pragma("unroll")                                                          \
    for (int nt = 0; nt < 8; ++nt) {                                           \
      size_t wb = (size_t)(MAT)*WMAT + (((ks * 8 + nt) * 64 + lane) * 8);      \
      short8 bh = *(const short8*)(Wfh + wb);                                  \
      short8 bl = *(const short8*)(Wfl + wb);                                  \
      _Pragma("unroll")                                                        \
      for (int mt = 0; mt < 2; ++mt) {                                         \
        acc[mt][nt] = __builtin_amdgcn_mfma_f32_16x16x32_bf16(ah[mt], bh, acc[mt][nt], 0, 0, 0); \
        acc[mt][nt] = __builtin_amdgcn_mfma_f32_16x16x32_bf16(al[mt], bh, acc[mt][nt], 0, 0, 0); \
        acc[mt][nt] = __builtin_amdgcn_mfma_f32_16x16x32_bf16(ah[mt], bl, acc[mt][nt], 0, 0, 0); \
      }                                                                        \
    }                                                                          \
  }

  // --- V = X @ in_v^T + b_v  -> bf16 seq ---
  GEMM_X(4)
  #pragma unroll
  for (int mt = 0; mt < 2; ++mt)
    #pragma unroll
    for (int reg = 0; reg < 4; ++reg) {
      size_t r8 = (size_t)ro[mt][reg] * 128;
      #pragma unroll
      for (int nt = 0; nt < 8; ++nt) {
        int j = nt * 16 + lrow;
        Vb[r8 + j] = f2bf_rne(acc[mt][nt][reg] + in_b[256 + j]);
      }
    }

  // --- Hq = relu(X @ Wq^T + bq) -> LDS (wave-private rows) ---
  GEMM_X(0)
  #pragma unroll
  for (int mt = 0; mt < 2; ++mt)
    #pragma unroll
    for (int reg = 0; reg < 4; ++reg) {
      int row = wave * 32 + mt * 16 + quad * 4 + reg;
      #pragma unroll
      for (int nt = 0; nt < 8; ++nt) {
        int col = nt * 16 + lrow;
        unsigned short h, l;
        split_bf(fmaxf(acc[mt][nt][reg] + bq[col], 0.f), h, l);
        Th[row][col] = h; Tl[row][col] = l;
      }
    }
  // --- Q = Hq @ in_q^T + b_q2, * scale*log2e -> split pair seq ---
  GEMM_T(2)
  #pragma unroll
  for (int mt = 0; mt < 2; ++mt)
    #pragma unroll
    for (int reg = 0; reg < 4; ++reg) {
      size_t r8 = (size_t)ro[mt][reg] * 128;
      #pragma unroll
      for (int nt = 0; nt < 8; ++nt) {
        int j = nt * 16 + lrow;
        unsigned short h, l;
        split_bf((acc[mt][nt][reg] + in_b[j]) * scl2, h, l);
        Qh[r8 + j] = h; Ql[r8 + j] = l;
      }
    }

  // --- Hk = relu(X @ Wk^T + bk) -> LDS (overwrites; in-order DS per wave) ---
  GEMM_X(1)
  #pragma unroll
  for (int mt = 0; mt < 2; ++mt)
    #pragma unroll
    for (int reg = 0; reg < 4; ++reg) {
      int row = wave * 32 + mt * 16 + quad * 4 + reg;
      #pragma unroll
      for (int nt = 0; nt < 8; ++nt) {
        int col = nt * 16 + lrow;
        unsigned short h, l;
        split_bf(fmaxf(acc[mt][nt][reg] + bk[col], 0.f), h, l);
        Th[row][col] = h; Tl[row][col] = l;
      }
    }
  // --- K = Hk @ in_k^T + b_k2 -> split pair seq ---
  GEMM_T(3)
  #pragma unroll
  for (int mt = 0; mt < 2; ++mt)
    #pragma unroll
    for (int reg = 0; reg < 4; ++reg) {
      size_t r8 = (size_t)ro[mt][reg] * 128;
      #pragma unroll
      for (int nt = 0; nt < 8; ++nt) {
        int j = nt * 16 + lrow;
        unsigned short h, l;
        split_bf(acc[mt][nt][reg] + in_b[128 + j], h, l);
        Kh[r8 + j] = h; Kl[r8 + j] = l;
      }
    }
#undef GEMM_X
#undef GEMM_T
}

// Out-GEMM: C = A(split,row-gather) @ W^T + b. Zero LDS, frag-ready W.
__global__ __launch_bounds__(256, 2)
void k_out(const unsigned short* __restrict__ Ah, const unsigned short* __restrict__ Al,
           const int* __restrict__ rowmap,
           const unsigned short* __restrict__ Wfh, const unsigned short* __restrict__ Wfl,
           const float* __restrict__ bias,
           float* __restrict__ Cx, float* __restrict__ Cm) {
  const int tid = threadIdx.x;
  const int wave = tid >> 6;
  const int lane = tid & 63;
  const int lrow = lane & 15;
  const int quad = lane >> 4;
  const int t0 = blockIdx.x * 128;

  size_t aoff[2];
  #pragma unroll
  for (int mt = 0; mt < 2; ++mt) {
    int m = t0 + wave * 32 + mt * 16 + lrow;
    aoff[mt] = (size_t)rowmap[m] * 128 + quad * 8;
  }

  f32x4 acc[2][8];
  #pragma unroll
  for (int mt = 0; mt < 2; ++mt)
    #pragma unroll
    for (int nt = 0; nt < 8; ++nt) acc[mt][nt] = (f32x4){0.f, 0.f, 0.f, 0.f};

  #pragma unroll
  for (int ks = 0; ks < 4; ++ks) {
    short8 ah[2], al[2];
    #pragma unroll
    for (int mt = 0; mt < 2; ++mt) {
      ah[mt] = *(const short8*)(Ah + aoff[mt] + ks * 32);
      al[mt] = *(const short8*)(Al + aoff[mt] + ks * 32);
    }
    #pragma unroll
    for (int nt = 0; nt < 8; ++nt) {
      size_t wb = (size_t)(((ks * 8 + nt) * 64 + lane) * 8);
      short8 bh = *(const short8*)(Wfh + wb);
      short8 bl = *(const short8*)(Wfl + wb);
      #pragma unroll
      for (int mt = 0; mt < 2; ++mt) {
        acc[mt][nt] = __builtin_amdgcn_mfma_f32_16x16x32_bf16(ah[mt], bh, acc[mt][nt], 0, 0, 0);
        acc[mt][nt] = __builtin_amdgcn_mfma_f32_16x16x32_bf16(al[mt], bh, acc[mt][nt], 0, 0, 0);
        acc[mt][nt] = __builtin_amdgcn_mfma_f32_16x16x32_bf16(ah[mt], bl, acc[mt][nt], 0, 0, 0);
      }
    }
  }

  #pragma unroll
  for (int mt = 0; mt < 2; ++mt)
    #pragma unroll
    for (int reg = 0; reg < 4; ++reg) {
      int t = t0 + wave * 32 + mt * 16 + quad * 4 + reg;
      float* cp = (t < NB) ? Cm + (size_t)t * E : Cx + (size_t)(t - NB) * E;
      #pragma unroll
      for (int nt = 0; nt < 8; ++nt) {
        int j = nt * 16 + lrow;
        cp[j] = acc[mt][nt][reg] + bias[j];
      }
    }
}

// Flash attention: grid (NB, 6), 4 waves = 4 heads, 32 queries/block.
__global__ __launch_bounds__(256, 3)
void k_flash(const unsigned short* __restrict__ Qh, const unsigned short* __restrict__ Ql,
             const unsigned short* __restrict__ Kh, const unsigned short* __restrict__ Kl,
             const unsigned short* __restrict__ Vb, const int* __restrict__ start,
             unsigned short* __restrict__ ctxh, unsigned short* __restrict__ ctxl) {
  __shared__ unsigned short Vlds[32][134];
  __shared__ unsigned short Pld[4][2][32][40];
  const int g = blockIdx.x;
  const int tid = threadIdx.x;
  const int wv = tid >> 6;
  const int lane = tid & 63;
  const int lrow = lane & 15;
  const int quad = lane >> 4;
  const int s0 = start[g];
  const int c = start[g + 1] - s0 + 1;
  const int sbase = s0 + g;
  const int hoff = wv * 32 + quad * 8;

  for (int qb = 32 * blockIdx.y; qb < c; qb += 32 * gridDim.y) {
    short8 qfh[2], qfl[2];
    #pragma unroll
    for (int mt = 0; mt < 2; ++mt) {
      int qs = qb + mt * 16 + lrow; if (qs >= c) qs = 0;
      size_t off = (size_t)(sbase + qs) * 128 + hoff;
      qfh[mt] = *(const short8*)(Qh + off);
      qfl[mt] = *(const short8*)(Ql + off);
    }
    float mr[2][4], lr[2][4];
    f32x4 O[2][2];
    #pragma unroll
    for (int mt = 0; mt < 2; ++mt) {
      #pragma unroll
      for (int r4 = 0; r4 < 4; ++r4) { mr[mt][r4] = -3.0e38f; lr[mt][r4] = 0.f; }
      O[mt][0] = (f32x4){0.f, 0.f, 0.f, 0.f};
      O[mt][1] = (f32x4){0.f, 0.f, 0.f, 0.f};
    }

    const int nch = (c + 31) >> 5;
    for (int ch = 0; ch < nch; ++ch) {
      const int kb = ch * 32;
      short8 kfh[2], kfl[2];
      #pragma unroll
      for (int s = 0; s < 2; ++s) {
        int ks = kb + s * 16 + lrow; if (ks >= c) ks = 0;
        size_t off = (size_t)(sbase + ks) * 128 + hoff;
        kfh[s] = *(const short8*)(Kh + off);
        kfl[s] = *(const short8*)(Kl + off);
      }
      __syncthreads();
      #pragma unroll
      for (int r = 0; r < 2; ++r) {
        int key = r * 16 + (tid >> 4);
        int seg = tid & 15;
        int ks = kb + key; if (ks >= c) ks = 0;
        uint4 v = *(const uint4*)(Vb + (size_t)(sbase + ks) * 128 + seg * 8);
        unsigned* dst = (unsigned*)&Vlds[key][seg * 8];
        dst[0] = v.x; dst[1] = v.y; dst[2] = v.z; dst[3] = v.w;
      }
      __syncthreads();

      f32x4 sv[2][2];
      #pragma unroll
      for (int mt = 0; mt < 2; ++mt)
        #pragma unroll
        for (int s = 0; s < 2; ++s) {
          f32x4 z = (f32x4){0.f, 0.f, 0.f, 0.f};
          z = __builtin_amdgcn_mfma_f32_16x16x32_bf16(qfh[mt], kfh[s], z, 0, 0, 0);
          z = __builtin_amdgcn_mfma_f32_16x16x32_bf16(qfl[mt], kfh[s], z, 0, 0, 0);
          z = __builtin_amdgcn_mfma_f32_16x16x32_bf16(qfh[mt], kfl[s], z, 0, 0, 0);
          sv[mt][s] = z;
        }
      const bool v0 = (kb + lrow) < c;
      const bool v1 = (kb + 16 + lrow) < c;

      #pragma unroll
      for (int mt = 0; mt < 2; ++mt) {
        float mn[4], al[4], p0[4], p1[4], rs[4];
        #pragma unroll
        for (int r4 = 0; r4 < 4; ++r4) {
          float a = v0 ? sv[mt][0][r4] : -3.0e38f;
          float b = v1 ? sv[mt][1][r4] : -3.0e38f;
          sv[mt][0][r4] = a; sv[mt][1][r4] = b;
          mn[r4] = fmaxf(mr[mt][r4], fmaxf(a, b));
        }
        #pragma unroll
        for (int st = 1; st < 16; st <<= 1)
          #pragma unroll
          for (int r4 = 0; r4 < 4; ++r4)
            mn[r4] = fmaxf(mn[r4], __shfl_xor(mn[r4], st, 16));
        #pragma unroll
        for (int r4 = 0; r4 < 4; ++r4) {
          al[r4] = exp2f(mr[mt][r4] - mn[r4]);
          p0[r4] = exp2f(sv[mt][0][r4] - mn[r4]);
          p1[r4] = exp2f(sv[mt][1][r4] - mn[r4]);
          rs[r4] = p0[r4] + p1[r4];
          mr[mt][r4] = mn[r4];
        }
        #pragma unroll
        for (int st = 1; st < 16; st <<= 1)
          #pragma unroll
          for (int r4 = 0; r4 < 4; ++r4)
            rs[r4] += __shfl_xor(rs[r4], st, 16);
        #pragma unroll
        for (int r4 = 0; r4 < 4; ++r4) {
          lr[mt][r4] = lr[mt][r4] * al[r4] + rs[r4];
          int row = mt * 16 + quad * 4 + r4;
          unsigned short h, l;
          split_bf(p0[r4], h, l);
          Pld[wv][0][row][lrow] = h; Pld[wv][1][row][lrow] = l;
          split_bf(p1[r4], h, l);
          Pld[wv][0][row][lrow + 16] = h; Pld[wv][1][row][lrow + 16] = l;
          O[mt][0][r4] *= al[r4];
          O[mt][1][r4] *= al[r4];
        }
      }

      short8 vf[2];
      #pragma unroll
      for (int nt = 0; nt < 2; ++nt)
        #pragma unroll
        for (int jj = 0; jj < 8; ++jj)
          vf[nt][jj] = (short)Vlds[quad * 8 + jj][wv * 32 + nt * 16 + lrow];

      #pragma unroll
      for (int mt = 0; mt < 2; ++mt) {
        short8 ph = *(const short8*)&Pld[wv][0][mt * 16 + lrow][quad * 8];
        short8 pl = *(const short8*)&Pld[wv][1][mt * 16 + lrow][quad * 8];
        #pragma unroll
        for (int nt = 0; nt < 2; ++nt) {
          O[mt][nt] = __builtin_amdgcn_mfma_f32_16x16x32_bf16(ph, vf[nt], O[mt][nt], 0, 0, 0);
          O[mt][nt] = __builtin_amdgcn_mfma_f32_16x16x32_bf16(pl, vf[nt], O[mt][nt], 0, 0, 0);
        }
      }
    }

    #pragma unroll
    for (int mt = 0; mt < 2; ++mt)
      #pragma unroll
      for (int r4 = 0; r4 < 4; ++r4) {
        int qs = qb + mt * 16 + quad * 4 + r4;
        if (qs < c) {
          float inv = 1.f / lr[mt][r4];
          size_t off = (size_t)(sbase + qs) * 128 + wv * 32 + lrow;
          unsigned short h, l;
          split_bf(O[mt][0][r4] * inv, h, l);
          ctxh[off] = h; ctxl[off] = l;
          split_bf(O[mt][1][r4] * inv, h, l);
          ctxh[off + 16] = h; ctxl[off + 16] = l;
        }
      }
  }
}

extern "C" void kernel_launch(void* const* d_in, const int* in_sizes, int n_in,
                              void* d_out, int out_size, void* d_ws, size_t ws_size,
                              hipStream_t stream) {
  const float* x       = (const float*)d_in[0];
  const float* metal_x = (const float*)d_in[1];
  const int*   batch   = (const int*)d_in[2];
  const float* Wk      = (const float*)d_in[3];
  const float* bk      = (const float*)d_in[4];
  const float* Wq      = (const float*)d_in[5];
  const float* bq      = (const float*)d_in[6];
  const float* in_w    = (const float*)d_in[7];
  const float* in_b    = (const float*)d_in[8];
  const float* out_w   = (const float*)d_in[9];
  const float* out_b   = (const float*)d_in[10];
  float* out = (float*)d_out;

  // ---- workspace layout (float offsets) ----
  // [0,528) start | [528,66576) seqmap | [66576,164880) Wfh+Wfl (98304 FLOATS)
  // BUF0+[0,TE): ctx split pair | +[TE,2TE): Q pair | +[2TE,3TE): K pair
  // +[3TE,3.5TE): V bf16.  X split pair lives in d_out (TE floats exact).
  float* ws = (float*)d_ws;
  int* start  = (int*)d_ws;
  int* seqmap = (int*)(ws + 528);
  unsigned short* Wfh = (unsigned short*)(ws + 66576);
  unsigned short* Wfl = Wfh + 6 * WMAT;
  const size_t BUF0 = 164880;
  unsigned short* Ch  = (unsigned short*)(ws + BUF0);
  unsigned short* Cl  = Ch + TE;
  unsigned short* Qsh = (unsigned short*)(ws + BUF0 + TE);
  unsigned short* Qsl = Qsh + TE;
  unsigned short* Ksh = (unsigned short*)(ws + BUF0 + 2 * TE);
  unsigned short* Ksl = Ksh + TE;
  unsigned short* Vsb = (unsigned short*)(ws + BUF0 + 3 * TE);
  // peak ws = (164880 + 3.5*TE)*4 B ~= 119.0 MB (< 135.3 MB known-good)
  unsigned short* Xh = (unsigned short*)d_out;   // X split pair staged in d_out
  unsigned short* Xl = Xh + TE;

  k_starts<<<NN / 256, 256, 0, stream>>>(batch, start);
  k_seqmap<<<TT / 256, 256, 0, stream>>>(batch, start, seqmap);
  k_wconv<<<768 * 128 / 256, 256, 0, stream>>>(Wq, Wk, in_w, out_w, Wfh, Wfl);
  k_xsplit<<<TT / 8, 256, 0, stream>>>(x, metal_x, Xh, Xl);

  const float SCL2 = 0.17677669529663687f * 1.4426950408889634f;  // scale*log2(e)
  k_qkv<<<TT / 128, 256, 0, stream>>>(Xh, Xl, Wfh, Wfl, bq, bk, in_b, seqmap,
                                      Qsh, Qsl, Ksh, Ksl, Vsb, SCL2);

  dim3 agrid(NB, 6);
  k_flash<<<agrid, 256, 0, stream>>>(Qsh, Qsl, Ksh, Ksl, Vsb, start, Ch, Cl);

  // out = ctx @ out_w^T + b (rows gathered via seqmap), token-order output
  k_out<<<TT / 128, 256, 0, stream>>>(Ch, Cl, seqmap, Wfh + 5 * WMAT, Wfl + 5 * WMAT,
                                      out_b, out, out + (size_t)NN * E);
}

// Round 10
// 340.147 us; speedup vs baseline: 1.0978x; 1.0978x over previous
//
#include <hip/hip_runtime.h>

#define E   128
#define HD  32
#define NB  512
#define NN  65536
#define TT  (NB + NN)   // 66048 tokens: [0,NB) metal, [NB,TT) nodes
#define TE  ((size_t)TT * 128)
#define WMAT 16384      // shorts per matrix in frag-ready layout: 4*8*64*8

typedef __attribute__((ext_vector_type(8))) short short8;
typedef __attribute__((ext_vector_type(4))) float f32x4;

__device__ __forceinline__ unsigned short f2bf_rne(float x) {
  unsigned u = __float_as_uint(x);
  return (unsigned short)((u + 0x7FFFu + ((u >> 16) & 1u)) >> 16);
}
__device__ __forceinline__ void split_bf(float x, unsigned short& h, unsigned short& l) {
  h = f2bf_rne(x);
  float hf = __uint_as_float(((unsigned)h) << 16);
  l = f2bf_rne(x - hf);
}

// start[b] = first node index of graph b (batch sorted); start[NB] = NN.
__global__ void k_starts(const int* __restrict__ batch, int* __restrict__ start) {
  int i = blockIdx.x * blockDim.x + threadIdx.x;
  if (i >= NN) return;
  int bi = batch[i];
  int bp = (i == 0) ? -1 : batch[i - 1];
  for (int b = bp + 1; b <= bi; ++b) start[b] = i;
  if (i == NN - 1)
    for (int b = bi + 1; b <= NB; ++b) start[b] = NN;
}

// seq row of token t: metal g -> start[g]+g ; node i -> i + batch[i] + 1
__global__ void k_seqmap(const int* __restrict__ batch, const int* __restrict__ start,
                         int* __restrict__ seqmap) {
  int t = blockIdx.x * 256 + threadIdx.x;
  if (t >= TT) return;
  seqmap[t] = (t < NB) ? (start[t] + t) : (t - NB + batch[t - NB] + 1);
}

// Split weights to hi/lo bf16 in MFMA-frag-ready order:
//   Wf[mat][ks][nt][lane][jj]; mat: 0=Wq 1=Wk 2=in_q 3=in_k 4=in_v 5=out_w.
__global__ void k_wconv(const float* __restrict__ Wq, const float* __restrict__ Wk,
                        const float* __restrict__ in_w, const float* __restrict__ out_w,
                        unsigned short* __restrict__ Wfh, unsigned short* __restrict__ Wfl) {
  int idx = blockIdx.x * 256 + threadIdx.x;   // < 768*128
  int r = idx >> 7, k = idx & 127;
  float v;
  if (r < 128)      v = Wq[r * 128 + k];
  else if (r < 256) v = Wk[(r - 128) * 128 + k];
  else if (r < 640) v = in_w[(r - 256) * 128 + k];
  else              v = out_w[(r - 640) * 128 + k];
  unsigned short h, l;
  split_bf(v, h, l);
  int mat = r >> 7, j = r & 127;
  int ks = k >> 5, quad = (k >> 3) & 3, jj = k & 7;
  int nt = j >> 4, lrow = j & 15;
  int lane = quad * 16 + lrow;
  size_t di = (size_t)mat * WMAT + (((ks * 8 + nt) * 64 + lane) * 8 + jj);
  Wfh[di] = h;
  Wfl[di] = l;
}

// Pre-split token matrix (metal then nodes) into bf16 hi/lo, token order.
__global__ void k_xsplit(const float* __restrict__ x, const float* __restrict__ metal_x,
                         unsigned short* __restrict__ Xh, unsigned short* __restrict__ Xl) {
  int i = blockIdx.x * 256 + threadIdx.x;     // < TT*32
  int t = i >> 5, seg = i & 31;
  const float* src = (t < NB) ? metal_x + (size_t)t * E + seg * 4
                              : x + (size_t)(t - NB) * E + seg * 4;
  float4 v = *(const float4*)src;
  unsigned short h0, l0, h1, l1, h2, l2, h3, l3;
  split_bf(v.x, h0, l0); split_bf(v.y, h1, l1);
  split_bf(v.z, h2, l2); split_bf(v.w, h3, l3);
  ushort4 hv = {h0, h1, h2, h3}, lv = {l0, l1, l2, l3};
  *(ushort4*)(Xh + (size_t)i * 4) = hv;
  *(ushort4*)(Xl + (size_t)i * 4) = lv;
}

// Fused QKV, 64-row tiles (LDS 34.8 KB -> 4 blocks/CU, 16 waves/CU).
// Per block: V, Hq->Q, Hk->K with split-bf16 MFMA. X pre-split (pure loads).
// Hq/Hk round-trip through wave-private LDS rows (no barriers).
__global__ __launch_bounds__(256, 4)
void k_qkv(const unsigned short* __restrict__ Xh, const unsigned short* __restrict__ Xl,
           const unsigned short* __restrict__ Wfh, const unsigned short* __restrict__ Wfl,
           const float* __restrict__ bq, const float* __restrict__ bk,
           const float* __restrict__ in_b, const int* __restrict__ seqmap,
           unsigned short* __restrict__ Qh, unsigned short* __restrict__ Ql,
           unsigned short* __restrict__ Kh, unsigned short* __restrict__ Kl,
           unsigned short* __restrict__ Vb, float scl2) {
  __shared__ unsigned short Th[64][136];   // 17408 B
  __shared__ unsigned short Tl[64][136];   // 17408 B ; total 34816 B -> 4 blocks/CU
  const int tid = threadIdx.x;
  const int wave = tid >> 6;
  const int lane = tid & 63;
  const int lrow = lane & 15;
  const int quad = lane >> 4;
  const int t0 = blockIdx.x * 64;
  const int wrow = wave * 16;              // this wave's private 16-row band

  // X A-frags for all ks (regs; reused by V, Hq, Hk phases).
  short8 xh[4], xl[4];
  {
    size_t ao = (size_t)(t0 + wrow + lrow) * 128 + quad * 8;
    #pragma unroll
    for (int ks = 0; ks < 4; ++ks) {
      xh[ks] = *(const short8*)(Xh + ao + ks * 32);
      xl[ks] = *(const short8*)(Xl + ao + ks * 32);
    }
  }
  int ro[4];
  #pragma unroll
  for (int reg = 0; reg < 4; ++reg)
    ro[reg] = seqmap[t0 + wrow + quad * 4 + reg];

  f32x4 acc[8];

#define GEMM_X(MAT)                                                            \
  _Pragma("unroll")                                                            \
  for (int nt = 0; nt < 8; ++nt) acc[nt] = (f32x4){0.f, 0.f, 0.f, 0.f};        \
  _Pragma("unroll")                                                            \
  for (int ks = 0; ks < 4; ++ks)                                               \
    _Pragma("unroll")                                                          \
    for (int nt = 0; nt < 8; ++nt) {                                           \
      size_t wb = (size_t)(MAT)*WMAT + (((ks * 8 + nt) * 64 + lane) * 8);      \
      short8 bh = *(const short8*)(Wfh + wb);                                  \
      short8 bl = *(const short8*)(Wfl + wb);                                  \
      acc[nt] = __builtin_amdgcn_mfma_f32_16x16x32_bf16(xh[ks], bh, acc[nt], 0, 0, 0); \
      acc[nt] = __builtin_amdgcn_mfma_f32_16x16x32_bf16(xl[ks], bh, acc[nt], 0, 0, 0); \
      acc[nt] = __builtin_amdgcn_mfma_f32_16x16x32_bf16(xh[ks], bl, acc[nt], 0, 0, 0); \
    }

#define GEMM_T(MAT)                                                            \
  _Pragma("unroll")                                                            \
  for (int nt = 0; nt < 8; ++nt) acc[nt] = (f32x4){0.f, 0.f, 0.f, 0.f};        \
  _Pragma("unroll")                                                            \
  for (int ks = 0; ks < 4; ++ks) {                                             \
    short8 ah = *(const short8*)&Th[wrow + lrow][ks * 32 + quad * 8];          \
    short8 al = *(const short8*)&Tl[wrow + lrow][ks * 32 + quad * 8];          \
    _Pragma("unroll")                                                          \
    for (int nt = 0; nt < 8; ++nt) {                                           \
      size_t wb = (size_t)(MAT)*WMAT + (((ks * 8 + nt) * 64 + lane) * 8);      \
      short8 bh = *(const short8*)(Wfh + wb);                                  \
      short8 bl = *(const short8*)(Wfl + wb);                                  \
      acc[nt] = __builtin_amdgcn_mfma_f32_16x16x32_bf16(ah, bh, acc[nt], 0, 0, 0); \
      acc[nt] = __builtin_amdgcn_mfma_f32_16x16x32_bf16(al, bh, acc[nt], 0, 0, 0); \
      acc[nt] = __builtin_amdgcn_mfma_f32_16x16x32_bf16(ah, bl, acc[nt], 0, 0, 0); \
    }                                                                          \
  }

  // --- V = X @ in_v^T + b_v  -> bf16 seq ---
  GEMM_X(4)
  #pragma unroll
  for (int reg = 0; reg < 4; ++reg) {
    size_t r8 = (size_t)ro[reg] * 128;
    #pragma unroll
    for (int nt = 0; nt < 8; ++nt) {
      int j = nt * 16 + lrow;
      Vb[r8 + j] = f2bf_rne(acc[nt][reg] + in_b[256 + j]);
    }
  }

  // --- Hq = relu(X @ Wq^T + bq) -> LDS (wave-private rows) ---
  GEMM_X(0)
  #pragma unroll
  for (int reg = 0; reg < 4; ++reg) {
    int row = wrow + quad * 4 + reg;
    #pragma unroll
    for (int nt = 0; nt < 8; ++nt) {
      int col = nt * 16 + lrow;
      unsigned short h, l;
      split_bf(fmaxf(acc[nt][reg] + bq[col], 0.f), h, l);
      Th[row][col] = h; Tl[row][col] = l;
    }
  }
  // --- Q = Hq @ in_q^T + b, * scale*log2e -> split pair seq ---
  GEMM_T(2)
  #pragma unroll
  for (int reg = 0; reg < 4; ++reg) {
    size_t r8 = (size_t)ro[reg] * 128;
    #pragma unroll
    for (int nt = 0; nt < 8; ++nt) {
      int j = nt * 16 + lrow;
      unsigned short h, l;
      split_bf((acc[nt][reg] + in_b[j]) * scl2, h, l);
      Qh[r8 + j] = h; Ql[r8 + j] = l;
    }
  }

  // --- Hk = relu(X @ Wk^T + bk) -> LDS (overwrite; in-order DS per wave) ---
  GEMM_X(1)
  #pragma unroll
  for (int reg = 0; reg < 4; ++reg) {
    int row = wrow + quad * 4 + reg;
    #pragma unroll
    for (int nt = 0; nt < 8; ++nt) {
      int col = nt * 16 + lrow;
      unsigned short h, l;
      split_bf(fmaxf(acc[nt][reg] + bk[col], 0.f), h, l);
      Th[row][col] = h; Tl[row][col] = l;
    }
  }
  // --- K = Hk @ in_k^T + b -> split pair seq ---
  GEMM_T(3)
  #pragma unroll
  for (int reg = 0; reg < 4; ++reg) {
    size_t r8 = (size_t)ro[reg] * 128;
    #pragma unroll
    for (int nt = 0; nt < 8; ++nt) {
      int j = nt * 16 + lrow;
      unsigned short h, l;
      split_bf(acc[nt][reg] + in_b[128 + j], h, l);
      Kh[r8 + j] = h; Kl[r8 + j] = l;
    }
  }
#undef GEMM_X
#undef GEMM_T
}

// Out-GEMM: C = A(split,row-gather) @ W^T + b. Zero LDS, frag-ready W.
__global__ __launch_bounds__(256, 2)
void k_out(const unsigned short* __restrict__ Ah, const unsigned short* __restrict__ Al,
           const int* __restrict__ rowmap,
           const unsigned short* __restrict__ Wfh, const unsigned short* __restrict__ Wfl,
           const float* __restrict__ bias,
           float* __restrict__ Cx, float* __restrict__ Cm) {
  const int tid = threadIdx.x;
  const int wave = tid >> 6;
  const int lane = tid & 63;
  const int lrow = lane & 15;
  const int quad = lane >> 4;
  const int t0 = blockIdx.x * 128;

  size_t aoff[2];
  #pragma unroll
  for (int mt = 0; mt < 2; ++mt) {
    int m = t0 + wave * 32 + mt * 16 + lrow;
    aoff[mt] = (size_t)rowmap[m] * 128 + quad * 8;
  }

  f32x4 acc[2][8];
  #pragma unroll
  for (int mt = 0; mt < 2; ++mt)
    #pragma unroll
    for (int nt = 0; nt < 8; ++nt) acc[mt][nt] = (f32x4){0.f, 0.f, 0.f, 0.f};

  #pragma unroll
  for (int ks = 0; ks < 4; ++ks) {
    short8 ah[2], al[2];
    #pragma unroll
    for (int mt = 0; mt < 2; ++mt) {
      ah[mt] = *(const short8*)(Ah + aoff[mt] + ks * 32);
      al[mt] = *(const short8*)(Al + aoff[mt] + ks * 32);
    }
    #pragma unroll
    for (int nt = 0; nt < 8; ++nt) {
      size_t wb = (size_t)(((ks * 8 + nt) * 64 + lane) * 8);
      short8 bh = *(const short8*)(Wfh + wb);
      short8 bl = *(const short8*)(Wfl + wb);
      #pragma unroll
      for (int mt = 0; mt < 2; ++mt) {
        acc[mt][nt] = __builtin_amdgcn_mfma_f32_16x16x32_bf16(ah[mt], bh, acc[mt][nt], 0, 0, 0);
        acc[mt][nt] = __builtin_amdgcn_mfma_f32_16x16x32_bf16(al[mt], bh, acc[mt][nt], 0, 0, 0);
        acc[mt][nt] = __builtin_amdgcn_mfma_f32_16x16x32_bf16(ah[mt], bl, acc[mt][nt], 0, 0, 0);
      }
    }
  }

  #pragma unroll
  for (int mt = 0; mt < 2; ++mt)
    #pragma unroll
    for (int reg = 0; reg < 4; ++reg) {
      int t = t0 + wave * 32 + mt * 16 + quad * 4 + reg;
      float* cp = (t < NB) ? Cm + (size_t)t * E : Cx + (size_t)(t - NB) * E;
      #pragma unroll
      for (int nt = 0; nt < 8; ++nt) {
        int j = nt * 16 + lrow;
        cp[j] = acc[mt][nt][reg] + bias[j];
      }
    }
}

// Flash attention: grid (NB, 6), 4 waves = 4 heads, 32 queries/block.
__global__ __launch_bounds__(256, 3)
void k_flash(const unsigned short* __restrict__ Qh, const unsigned short* __restrict__ Ql,
             const unsigned short* __restrict__ Kh, const unsigned short* __restrict__ Kl,
             const unsigned short* __restrict__ Vb, const int* __restrict__ start,
             unsigned short* __restrict__ ctxh, unsigned short* __restrict__ ctxl) {
  __shared__ unsigned short Vlds[32][134];
  __shared__ unsigned short Pld[4][2][32][40];
  const int g = blockIdx.x;
  const int tid = threadIdx.x;
  const int wv = tid >> 6;
  const int lane = tid & 63;
  const int lrow = lane & 15;
  const int quad = lane >> 4;
  const int s0 = start[g];
  const int c = start[g + 1] - s0 + 1;
  const int sbase = s0 + g;
  const int hoff = wv * 32 + quad * 8;

  for (int qb = 32 * blockIdx.y; qb < c; qb += 32 * gridDim.y) {
    short8 qfh[2], qfl[2];
    #pragma unroll
    for (int mt = 0; mt < 2; ++mt) {
      int qs = qb + mt * 16 + lrow; if (qs >= c) qs = 0;
      size_t off = (size_t)(sbase + qs) * 128 + hoff;
      qfh[mt] = *(const short8*)(Qh + off);
      qfl[mt] = *(const short8*)(Ql + off);
    }
    float mr[2][4], lr[2][4];
    f32x4 O[2][2];
    #pragma unroll
    for (int mt = 0; mt < 2; ++mt) {
      #pragma unroll
      for (int r4 = 0; r4 < 4; ++r4) { mr[mt][r4] = -3.0e38f; lr[mt][r4] = 0.f; }
      O[mt][0] = (f32x4){0.f, 0.f, 0.f, 0.f};
      O[mt][1] = (f32x4){0.f, 0.f, 0.f, 0.f};
    }

    const int nch = (c + 31) >> 5;
    for (int ch = 0; ch < nch; ++ch) {
      const int kb = ch * 32;
      short8 kfh[2], kfl[2];
      #pragma unroll
      for (int s = 0; s < 2; ++s) {
        int ks = kb + s * 16 + lrow; if (ks >= c) ks = 0;
        size_t off = (size_t)(sbase + ks) * 128 + hoff;
        kfh[s] = *(const short8*)(Kh + off);
        kfl[s] = *(const short8*)(Kl + off);
      }
      __syncthreads();
      #pragma unroll
      for (int r = 0; r < 2; ++r) {
        int key = r * 16 + (tid >> 4);
        int seg = tid & 15;
        int ks = kb + key; if (ks >= c) ks = 0;
        uint4 v = *(const uint4*)(Vb + (size_t)(sbase + ks) * 128 + seg * 8);
        unsigned* dst = (unsigned*)&Vlds[key][seg * 8];
        dst[0] = v.x; dst[1] = v.y; dst[2] = v.z; dst[3] = v.w;
      }
      __syncthreads();

      f32x4 sv[2][2];
      #pragma unroll
      for (int mt = 0; mt < 2; ++mt)
        #pragma unroll
        for (int s = 0; s < 2; ++s) {
          f32x4 z = (f32x4){0.f, 0.f, 0.f, 0.f};
          z = __builtin_amdgcn_mfma_f32_16x16x32_bf16(qfh[mt], kfh[s], z, 0, 0, 0);
          z = __builtin_amdgcn_mfma_f32_16x16x32_bf16(qfl[mt], kfh[s], z, 0, 0, 0);
          z = __builtin_amdgcn_mfma_f32_16x16x32_bf16(qfh[mt], kfl[s], z, 0, 0, 0);
          sv[mt][s] = z;
        }
      const bool v0 = (kb + lrow) < c;
      const bool v1 = (kb + 16 + lrow) < c;

      #pragma unroll
      for (int mt = 0; mt < 2; ++mt) {
        float mn[4], al[4], p0[4], p1[4], rs[4];
        #pragma unroll
        for (int r4 = 0; r4 < 4; ++r4) {
          float a = v0 ? sv[mt][0][r4] : -3.0e38f;
          float b = v1 ? sv[mt][1][r4] : -3.0e38f;
          sv[mt][0][r4] = a; sv[mt][1][r4] = b;
          mn[r4] = fmaxf(mr[mt][r4], fmaxf(a, b));
        }
        #pragma unroll
        for (int st = 1; st < 16; st <<= 1)
          #pragma unroll
          for (int r4 = 0; r4 < 4; ++r4)
            mn[r4] = fmaxf(mn[r4], __shfl_xor(mn[r4], st, 16));
        #pragma unroll
        for (int r4 = 0; r4 < 4; ++r4) {
          al[r4] = exp2f(mr[mt][r4] - mn[r4]);
          p0[r4] = exp2f(sv[mt][0][r4] - mn[r4]);
          p1[r4] = exp2f(sv[mt][1][r4] - mn[r4]);
          rs[r4] = p0[r4] + p1[r4];
          mr[mt][r4] = mn[r4];
        }
        #pragma unroll
        for (int st = 1; st < 16; st <<= 1)
          #pragma unroll
          for (int r4 = 0; r4 < 4; ++r4)
            rs[r4] += __shfl_xor(rs[r4], st, 16);
        #pragma unroll
        for (int r4 = 0; r4 < 4; ++r4) {
          lr[mt][r4] = lr[mt][r4] * al[r4] + rs[r4];
          int row = mt * 16 + quad * 4 + r4;
          unsigned short h, l;
          split_bf(p0[r4], h, l);
          Pld[wv][0][row][lrow] = h; Pld[wv][1][row][lrow] = l;
          split_bf(p1[r4], h, l);
          Pld[wv][0][row][lrow + 16] = h; Pld[wv][1][row][lrow + 16] = l;
          O[mt][0][r4] *= al[r4];
          O[mt][1][r4] *= al[r4];
        }
      }

      short8 vf[2];
      #pragma unroll
      for (int nt = 0; nt < 2; ++nt)
        #pragma unroll
        for (int jj = 0; jj < 8; ++jj)
          vf[nt][jj] = (short)Vlds[quad * 8 + jj][wv * 32 + nt * 16 + lrow];

      #pragma unroll
      for (int mt = 0; mt < 2; ++mt) {
        short8 ph = *(const short8*)&Pld[wv][0][mt * 16 + lrow][quad * 8];
        short8 pl = *(const short8*)&Pld[wv][1][mt * 16 + lrow][quad * 8];
        #pragma unroll
        for (int nt = 0; nt < 2; ++nt) {
          O[mt][nt] = __builtin_amdgcn_mfma_f32_16x16x32_bf16(ph, vf[nt], O[mt][nt], 0, 0, 0);
          O[mt][nt] = __builtin_amdgcn_mfma_f32_16x16x32_bf16(pl, vf[nt], O[mt][nt], 0, 0, 0);
        }
      }
    }

    #pragma unroll
    for (int mt = 0; mt < 2; ++mt)
      #pragma unroll
      for (int r4 = 0; r4 < 4; ++r4) {
        int qs = qb + mt * 16 + quad * 4 + r4;
        if (qs < c) {
          float inv = 1.f / lr[mt][r4];
          size_t off = (size_t)(sbase + qs) * 128 + wv * 32 + lrow;
          unsigned short h, l;
          split_bf(O[mt][0][r4] * inv, h, l);
          ctxh[off] = h; ctxl[off] = l;
          split_bf(O[mt][1][r4] * inv, h, l);
          ctxh[off + 16] = h; ctxl[off + 16] = l;
        }
      }
  }
}

extern "C" void kernel_launch(void* const* d_in, const int* in_sizes, int n_in,
                              void* d_out, int out_size, void* d_ws, size_t ws_size,
                              hipStream_t stream) {
  const float* x       = (const float*)d_in[0];
  const float* metal_x = (const float*)d_in[1];
  const int*   batch   = (const int*)d_in[2];
  const float* Wk      = (const float*)d_in[3];
  const float* bk      = (const float*)d_in[4];
  const float* Wq      = (const float*)d_in[5];
  const float* bq      = (const float*)d_in[6];
  const float* in_w    = (const float*)d_in[7];
  const float* in_b    = (const float*)d_in[8];
  const float* out_w   = (const float*)d_in[9];
  const float* out_b   = (const float*)d_in[10];
  float* out = (float*)d_out;

  // ---- workspace layout (float offsets) ----
  // [0,528) start | [528,66576) seqmap | [66576,164880) Wfh+Wfl (98304 FLOATS)
  // BUF0+[0,TE): ctx split pair | +[TE,2TE): Q pair | +[2TE,3TE): K pair
  // +[3TE,3.5TE): V bf16.  X split pair lives in d_out (TE floats exact).
  float* ws = (float*)d_ws;
  int* start  = (int*)d_ws;
  int* seqmap = (int*)(ws + 528);
  unsigned short* Wfh = (unsigned short*)(ws + 66576);
  unsigned short* Wfl = Wfh + 6 * WMAT;
  const size_t BUF0 = 164880;
  unsigned short* Ch  = (unsigned short*)(ws + BUF0);
  unsigned short* Cl  = Ch + TE;
  unsigned short* Qsh = (unsigned short*)(ws + BUF0 + TE);
  unsigned short* Qsl = Qsh + TE;
  unsigned short* Ksh = (unsigned short*)(ws + BUF0 + 2 * TE);
  unsigned short* Ksl = Ksh + TE;
  unsigned short* Vsb = (unsigned short*)(ws + BUF0 + 3 * TE);
  // peak ws ~= 119.0 MB (< 135.3 MB known-good)
  unsigned short* Xh = (unsigned short*)d_out;   // X split pair staged in d_out
  unsigned short* Xl = Xh + TE;

  k_starts<<<NN / 256, 256, 0, stream>>>(batch, start);
  k_seqmap<<<TT / 256, 256, 0, stream>>>(batch, start, seqmap);
  k_wconv<<<768 * 128 / 256, 256, 0, stream>>>(Wq, Wk, in_w, out_w, Wfh, Wfl);
  k_xsplit<<<TT / 8, 256, 0, stream>>>(x, metal_x, Xh, Xl);

  const float SCL2 = 0.17677669529663687f * 1.4426950408889634f;  // scale*log2(e)
  k_qkv<<<TT / 64, 256, 0, stream>>>(Xh, Xl, Wfh, Wfl, bq, bk, in_b, seqmap,
                                     Qsh, Qsl, Ksh, Ksl, Vsb, SCL2);

  dim3 agrid(NB, 6);
  k_flash<<<agrid, 256, 0, stream>>>(Qsh, Qsl, Ksh, Ksl, Vsb, start, Ch, Cl);

  // out = ctx @ out_w^T + b (rows gathered via seqmap), token-order output
  k_out<<<TT / 128, 256, 0, stream>>>(Ch, Cl, seqmap, Wfh + 5 * WMAT, Wfl + 5 * WMAT,
                                      out_b, out, out + (size_t)NN * E);
}